// Round 1
// baseline (2166.041 us; speedup 1.0000x reference)
//
#include <hip/hip_runtime.h>
#include <math.h>

#define W_ 256
#define H_ 256
#define HW 65536
#define CC 64

// ---------------- conv3x3 (64->64, pad 1) + sigmoid ----------------
// grid (16,16,4), block 256.  thread = one pixel, 64 output-channel accums.
// Weights indexed uniformly -> scalar loads on the SMEM pipe.
__global__ __launch_bounds__(256) void k_conv3x3_sig(
    const float* __restrict__ x, const float* __restrict__ w, float* __restrict__ out)
{
  const int tx = threadIdx.x & 15, ty = threadIdx.x >> 4;
  const int gx = (blockIdx.x << 4) + tx;
  const int gy = (blockIdx.y << 4) + ty;
  const int b  = blockIdx.z;

  const bool xm = gx > 0, xp = gx < W_ - 1, ym = gy > 0, yp = gy < H_ - 1;
  const int oxm = xm ? -1 : 0, oxp = xp ? 1 : 0;
  const int oym = ym ? -W_ : 0, oyp = yp ? W_ : 0;
  const float m00 = (ym && xm) ? 1.f : 0.f, m01 = ym ? 1.f : 0.f, m02 = (ym && xp) ? 1.f : 0.f;
  const float m10 = xm ? 1.f : 0.f,                               m12 = xp ? 1.f : 0.f;
  const float m20 = (yp && xm) ? 1.f : 0.f, m21 = yp ? 1.f : 0.f, m22 = (yp && xp) ? 1.f : 0.f;

  float acc[CC];
#pragma unroll
  for (int i = 0; i < CC; ++i) acc[i] = 0.f;

  const float* xb = x + ((size_t)b * CC) * HW + gy * W_ + gx;
  for (int ci = 0; ci < CC; ++ci) {
    const float* xc = xb + ci * HW;
    const float v00 = xc[oym + oxm] * m00, v01 = xc[oym] * m01, v02 = xc[oym + oxp] * m02;
    const float v10 = xc[oxm] * m10,       v11 = xc[0],         v12 = xc[oxp] * m12;
    const float v20 = xc[oyp + oxm] * m20, v21 = xc[oyp] * m21, v22 = xc[oyp + oxp] * m22;
    const float* wp = w + ci * 9;
#pragma unroll
    for (int co = 0; co < CC; ++co) {
      const float* wc = wp + co * 576;   // uniform index -> s_load
      float a = acc[co];
      a = fmaf(v00, wc[0], a); a = fmaf(v01, wc[1], a); a = fmaf(v02, wc[2], a);
      a = fmaf(v10, wc[3], a); a = fmaf(v11, wc[4], a); a = fmaf(v12, wc[5], a);
      a = fmaf(v20, wc[6], a); a = fmaf(v21, wc[7], a); a = fmaf(v22, wc[8], a);
      acc[co] = a;
    }
  }
  float* ob = out + ((size_t)b * CC) * HW + gy * W_ + gx;
#pragma unroll
  for (int co = 0; co < CC; ++co)
    ob[co * HW] = 1.f / (1.f + __expf(-acc[co]));
}

// ---------------- depthwise conv3x3 (groups=C, pad 1) ----------------
// grid (H, C, B), block 256 = one row; channel uniform per block -> scalar weights.
__global__ __launch_bounds__(256) void k_dwconv(
    const float* __restrict__ t, const float* __restrict__ wdw, float* __restrict__ out)
{
  const int x_ = threadIdx.x;
  const int y_ = blockIdx.x;
  const int c  = blockIdx.y;
  const int b  = blockIdx.z;
  const bool xm = x_ > 0, xp = x_ < W_ - 1, ym = y_ > 0, yp = y_ < H_ - 1;
  const int oxm = xm ? -1 : 0, oxp = xp ? 1 : 0, oym = ym ? -W_ : 0, oyp = yp ? W_ : 0;
  const float m00 = (ym && xm) ? 1.f : 0.f, m01 = ym ? 1.f : 0.f, m02 = (ym && xp) ? 1.f : 0.f;
  const float m10 = xm ? 1.f : 0.f,                               m12 = xp ? 1.f : 0.f;
  const float m20 = (yp && xm) ? 1.f : 0.f, m21 = yp ? 1.f : 0.f, m22 = (yp && xp) ? 1.f : 0.f;

  const size_t base = ((size_t)(b * CC + c)) * HW + y_ * W_ + x_;
  const float* tc = t + base;
  const float* wc = wdw + c * 9;
  float a = 0.f;
  a = fmaf(tc[oym + oxm] * m00, wc[0], a);
  a = fmaf(tc[oym      ] * m01, wc[1], a);
  a = fmaf(tc[oym + oxp] * m02, wc[2], a);
  a = fmaf(tc[      oxm] * m10, wc[3], a);
  a = fmaf(tc[0        ]      , wc[4], a);
  a = fmaf(tc[      oxp] * m12, wc[5], a);
  a = fmaf(tc[oyp + oxm] * m20, wc[6], a);
  a = fmaf(tc[oyp      ] * m21, wc[7], a);
  a = fmaf(tc[oyp + oxp] * m22, wc[8], a);
  out[base] = a;
}

// ---------------- channel mean: (B,64,H,W) -> (B,H,W) ----------------
__global__ __launch_bounds__(256) void k_cmean(
    const float* __restrict__ in, float* __restrict__ out)
{
  const int x_ = threadIdx.x;
  const int y_ = blockIdx.x;
  const int b  = blockIdx.y;
  const int p  = y_ * W_ + x_;
  float s = 0.f;
  for (int c = 0; c < CC; ++c) s += in[((size_t)(b * CC + c)) * HW + p];
  out[(size_t)b * HW + p] = s * (1.f / 64.f);
}

// ---------------- conv1x1 (64->64) ----------------
// grid (H, B), block 256.  float4 scalar weight loads: 4 FMA per s_load_dwordx4.
__global__ __launch_bounds__(256) void k_conv1x1(
    const float* __restrict__ in, const float* __restrict__ w, float* __restrict__ out)
{
  const int x_ = threadIdx.x;
  const int y_ = blockIdx.x;
  const int b  = blockIdx.y;
  const int p  = y_ * W_ + x_;
  const float* ib = in + (size_t)b * CC * HW + p;
  float acc[CC];
#pragma unroll
  for (int i = 0; i < CC; ++i) acc[i] = 0.f;
  for (int ci0 = 0; ci0 < CC; ci0 += 4) {
    const float v0 = ib[(ci0 + 0) * HW], v1 = ib[(ci0 + 1) * HW];
    const float v2 = ib[(ci0 + 2) * HW], v3 = ib[(ci0 + 3) * HW];
#pragma unroll
    for (int co = 0; co < CC; ++co) {
      const float4 wv = *reinterpret_cast<const float4*>(w + co * CC + ci0);
      acc[co] = fmaf(v0, wv.x, fmaf(v1, wv.y, fmaf(v2, wv.z, fmaf(v3, wv.w, acc[co]))));
    }
  }
  float* ob = out + (size_t)b * CC * HW + p;
#pragma unroll
  for (int co = 0; co < CC; ++co) ob[co * HW] = acc[co];
}

// ---------------- windowed attention + fused proj ----------------
// grid (nh*nw=1024, B), block 512 = 8 waves = 8 heads, one 8x8 window.
__global__ __launch_bounds__(512) void k_attn(
    const float* __restrict__ qb, const float* __restrict__ kb, const float* __restrict__ vb,
    const float* __restrict__ sIll, const float* __restrict__ sNoi,
    const float* __restrict__ temp, const float* __restrict__ wproj, float* __restrict__ out)
{
  __shared__ float K_lds[8][64][8];
  __shared__ float V_lds[8][64][8];
  __shared__ float O_lds[64][64];

  const int tid  = threadIdx.x;
  const int h    = tid >> 6;        // wave == head
  const int lane = tid & 63;        // window pixel index (i*8+j)
  const int b    = blockIdx.y;
  const int wy   = blockIdx.x >> 5, wx = blockIdx.x & 31;
  const int py   = lane >> 3, px = lane & 7;
  const int p    = (wy * 8 + py) * W_ + wx * 8 + px;

  const size_t cbase = ((size_t)b * CC + h * 8) * HW + p;

  // q: load, l2-normalize over d=8, scale by (1 + illum_scalar)
  float qv[8];
#pragma unroll
  for (int dd = 0; dd < 8; ++dd) qv[dd] = qb[cbase + dd * HW];
  float qn = 0.f;
#pragma unroll
  for (int dd = 0; dd < 8; ++dd) qn += qv[dd] * qv[dd];
  qn = fmaxf(sqrtf(qn), 1e-12f);
  const float qs = (1.f + sIll[(size_t)b * HW + p]) / qn;
#pragma unroll
  for (int dd = 0; dd < 8; ++dd) qv[dd] *= qs;

  // k: load, normalize, scale by clip(1 - noise_scalar, 0, 1); stage to LDS
  float kv[8];
#pragma unroll
  for (int dd = 0; dd < 8; ++dd) kv[dd] = kb[cbase + dd * HW];
  float kn = 0.f;
#pragma unroll
  for (int dd = 0; dd < 8; ++dd) kn += kv[dd] * kv[dd];
  kn = fmaxf(sqrtf(kn), 1e-12f);
  float ks = 1.f - sNoi[(size_t)b * HW + p];
  ks = fminf(fmaxf(ks, 0.f), 1.f) / kn;
#pragma unroll
  for (int dd = 0; dd < 8; ++dd) K_lds[h][lane][dd] = kv[dd] * ks;
#pragma unroll
  for (int dd = 0; dd < 8; ++dd) V_lds[h][lane][dd] = vb[cbase + dd * HW];

  __syncthreads();

  // scores: 64 keys, kept in registers
  const float sc = 0.3535533905932738f * temp[h];   // d^-0.5 * temperature[h]
  float s[64];
#pragma unroll
  for (int kk = 0; kk < 64; ++kk) {
    float d0 = 0.f;
#pragma unroll
    for (int dd = 0; dd < 8; ++dd) d0 = fmaf(qv[dd], K_lds[h][kk][dd], d0);
    s[kk] = d0 * sc;
  }
  // softmax over kk
  float m = s[0];
#pragma unroll
  for (int kk = 1; kk < 64; ++kk) m = fmaxf(m, s[kk]);
  float sum = 0.f;
#pragma unroll
  for (int kk = 0; kk < 64; ++kk) { s[kk] = __expf(s[kk] - m); sum += s[kk]; }
  const float inv = 1.f / sum;

  // PV, write to O_lds[channel][pixel]
#pragma unroll
  for (int dd = 0; dd < 8; ++dd) {
    float o = 0.f;
#pragma unroll
    for (int kk = 0; kk < 64; ++kk) o = fmaf(s[kk], V_lds[h][kk][dd], o);
    O_lds[h * 8 + dd][lane] = o * inv;
  }
  __syncthreads();

  // fused proj conv1x1: thread -> pixel=lane, co = h*8 + j
  float pacc[8];
#pragma unroll
  for (int j = 0; j < 8; ++j) pacc[j] = 0.f;
  for (int ci0 = 0; ci0 < CC; ci0 += 4) {
    const float v0 = O_lds[ci0 + 0][lane], v1 = O_lds[ci0 + 1][lane];
    const float v2 = O_lds[ci0 + 2][lane], v3 = O_lds[ci0 + 3][lane];
#pragma unroll
    for (int j = 0; j < 8; ++j) {
      const float4 wv = *reinterpret_cast<const float4*>(wproj + (h * 8 + j) * CC + ci0);
      pacc[j] = fmaf(v0, wv.x, fmaf(v1, wv.y, fmaf(v2, wv.z, fmaf(v3, wv.w, pacc[j]))));
    }
  }
#pragma unroll
  for (int j = 0; j < 8; ++j)
    out[((size_t)b * CC + h * 8 + j) * HW + p] = pacc[j];
}

extern "C" void kernel_launch(void* const* d_in, const int* in_sizes, int n_in,
                              void* d_out, int out_size, void* d_ws, size_t ws_size,
                              hipStream_t stream) {
  const float* x        = (const float*)d_in[0];
  const float* w_iem    = (const float*)d_in[1];
  const float* w_nem    = (const float*)d_in[2];
  const float* w_iem_dw = (const float*)d_in[3];
  const float* w_nem_dw = (const float*)d_in[4];
  const float* w_q      = (const float*)d_in[5];
  const float* w_k      = (const float*)d_in[6];
  const float* w_v      = (const float*)d_in[7];
  const float* w_proj   = (const float*)d_in[8];
  const float* temp     = (const float*)d_in[9];
  float* outp = (float*)d_out;

  float* wsf = (float*)d_ws;
  const size_t PL = (size_t)4 * CC * HW;      // 16,777,216 floats / plane
  float* bufT = wsf;                          // t (sigmoid conv) -> later q
  float* bufI = wsf + PL;                     // illum_map        -> later k
  float* bufN = wsf + 2 * PL;                 // noise_map        -> later v
  float* sI   = wsf + 3 * PL;                 // (B,H,W)
  float* sN   = sI + (size_t)4 * HW;

  dim3 b256(256), b512(512);

  k_conv3x3_sig<<<dim3(16, 16, 4), b256, 0, stream>>>(x, w_iem, bufT);
  k_dwconv     <<<dim3(256, 64, 4), b256, 0, stream>>>(bufT, w_iem_dw, bufI);
  k_cmean      <<<dim3(256, 4),     b256, 0, stream>>>(bufI, sI);

  k_conv3x3_sig<<<dim3(16, 16, 4), b256, 0, stream>>>(x, w_nem, bufT);
  k_dwconv     <<<dim3(256, 64, 4), b256, 0, stream>>>(bufT, w_nem_dw, bufN);
  k_cmean      <<<dim3(256, 4),     b256, 0, stream>>>(bufN, sN);

  k_conv1x1    <<<dim3(256, 4),     b256, 0, stream>>>(bufI, w_q, bufT);  // q
  k_conv1x1    <<<dim3(256, 4),     b256, 0, stream>>>(bufN, w_k, bufI);  // k
  k_conv1x1    <<<dim3(256, 4),     b256, 0, stream>>>(x,    w_v, bufN);  // v

  k_attn<<<dim3(1024, 4), b512, 0, stream>>>(bufT, bufI, bufN, sI, sN, temp, w_proj, outp);
}

// Round 2
// 815.640 us; speedup vs baseline: 2.6556x; 2.6556x over previous
//
#include <hip/hip_runtime.h>
#include <hip/hip_bf16.h>
#include <math.h>

#define W_ 256
#define H_ 256
#define HW 65536
#define CC 64

typedef __bf16 bf16x8v __attribute__((ext_vector_type(8)));
typedef float  f32x4   __attribute__((ext_vector_type(4)));

// ---------------- weight prep: (w_iem,w_nem) fp32 OIHW -> Bt[co128][k=tap*64+ci] bf16 ----------------
__global__ __launch_bounds__(256) void k_wprep(
    const float* __restrict__ wi, const float* __restrict__ wn, __hip_bfloat16* __restrict__ Bt)
{
  int i = blockIdx.x * 256 + threadIdx.x;
  if (i >= 128 * 576) return;
  int co = i / 576, k = i - co * 576;
  int tap = k >> 6, ci = k & 63;
  const float* src = (co < 64) ? wi : wn;
  int c = co & 63;
  Bt[i] = __float2bfloat16(src[(c * 64 + ci) * 9 + tap]);
}

// ---------------- fused dual conv3x3 (x -> sigmoid(conv(x,w_iem)), sigmoid(conv(x,w_nem))) via MFMA ----------------
// grid (4, 128, 4): col-tile(64px) x row-tile(2 rows) x batch. block 512 = 8 waves (4 co-waves x 2 px-waves).
// GEMM: D[co=128][px=128], K=576 (k = tap*64 + ci). A=weights (L2), B=im2col patches (LDS).
__global__ __launch_bounds__(512) void k_conv3x3x2_mfma(
    const float* __restrict__ x, const __hip_bfloat16* __restrict__ Bt,
    __hip_bfloat16* __restrict__ outI, __hip_bfloat16* __restrict__ outN)
{
  // LDS tile: t = r*66 + c (r: 4 input rows, c: 66 input cols), row stride 144 B (64 ci bf16 + 16B pad)
  __shared__ __align__(16) char lds[264 * 144];

  const int tid = threadIdx.x;
  const int b = blockIdx.z, ry = blockIdx.y, cx = blockIdx.x;
  const int y0 = ry * 2, x0 = cx * 64;

  // ---- stage input tile (fp32 -> bf16), rows y0-1..y0+2, cols x0-1..x0+64, all 64 ci ----
  const float* xb = x + (size_t)b * CC * HW;
  for (int e = tid; e < 4 * 64 * 66; e += 512) {
    int t1 = e / 66;            // r*64 + ci
    int c  = e - t1 * 66;
    int r  = t1 >> 6, ci = t1 & 63;
    int y  = y0 - 1 + r, xx = x0 - 1 + c;
    float v = 0.f;
    if ((unsigned)y < 256u && (unsigned)xx < 256u)
      v = xb[(size_t)ci * HW + y * W_ + xx];
    *(__hip_bfloat16*)(lds + (r * 66 + c) * 144 + ci * 2) = __float2bfloat16(v);
  }
  __syncthreads();

  const int wv = tid >> 6, lane = tid & 63;
  const int wn_ = wv & 3;          // co-wave: 4 waves x 32 co = 128
  const int wm_ = wv >> 2;         // px-wave: 2 waves x 64 px = 128
  const int cob = wn_ * 32;
  const int pxb = wm_ * 64;
  const int lg = lane >> 4, lr = lane & 15;

  // B-operand LDS base addrs per pixel-fragment (all K-steps are +imm from these)
  const char* pB[4];
#pragma unroll
  for (int pi = 0; pi < 4; ++pi) {
    int opx = (pxb + pi * 16 + lr) & 63;
    pB[pi] = lds + (wm_ * 66 + opx) * 144 + lg * 16;
  }
  // A-operand (weights) bases: row co = cob + ni*16 + lr, k chunk lg*8
  const __hip_bfloat16* wb0 = Bt + (size_t)(cob + lr) * 576 + lg * 8;
  const __hip_bfloat16* wb1 = wb0 + 16 * 576;

  f32x4 acc[2][4];
#pragma unroll
  for (int i = 0; i < 2; ++i)
#pragma unroll
    for (int j = 0; j < 4; ++j) acc[i][j] = (f32x4){0.f, 0.f, 0.f, 0.f};

#pragma unroll
  for (int tap = 0; tap < 9; ++tap) {
    const int dy = tap / 3, dx = tap - dy * 3;
#pragma unroll
    for (int half = 0; half < 2; ++half) {
      const int loff = (dy * 66 + dx) * 144 + half * 64;   // LDS imm offset
      const int koff = tap * 64 + half * 32;               // weight k offset (elements)
      bf16x8v a0 = *(const bf16x8v*)(wb0 + koff);
      bf16x8v a1 = *(const bf16x8v*)(wb1 + koff);
      bf16x8v b0 = *(const bf16x8v*)(pB[0] + loff);
      bf16x8v b1 = *(const bf16x8v*)(pB[1] + loff);
      bf16x8v b2 = *(const bf16x8v*)(pB[2] + loff);
      bf16x8v b3 = *(const bf16x8v*)(pB[3] + loff);
      acc[0][0] = __builtin_amdgcn_mfma_f32_16x16x32_bf16(a0, b0, acc[0][0], 0, 0, 0);
      acc[0][1] = __builtin_amdgcn_mfma_f32_16x16x32_bf16(a0, b1, acc[0][1], 0, 0, 0);
      acc[0][2] = __builtin_amdgcn_mfma_f32_16x16x32_bf16(a0, b2, acc[0][2], 0, 0, 0);
      acc[0][3] = __builtin_amdgcn_mfma_f32_16x16x32_bf16(a0, b3, acc[0][3], 0, 0, 0);
      acc[1][0] = __builtin_amdgcn_mfma_f32_16x16x32_bf16(a1, b0, acc[1][0], 0, 0, 0);
      acc[1][1] = __builtin_amdgcn_mfma_f32_16x16x32_bf16(a1, b1, acc[1][1], 0, 0, 0);
      acc[1][2] = __builtin_amdgcn_mfma_f32_16x16x32_bf16(a1, b2, acc[1][2], 0, 0, 0);
      acc[1][3] = __builtin_amdgcn_mfma_f32_16x16x32_bf16(a1, b3, acc[1][3], 0, 0, 0);
    }
  }

  // ---- epilogue: sigmoid, bf16 store.  D row = co (lg*4+r), col = pixel (lr) ----
  const int y = y0 + wm_;
#pragma unroll
  for (int ni = 0; ni < 2; ++ni) {
#pragma unroll
    for (int pi = 0; pi < 4; ++pi) {
      const int xx = x0 + ((pxb + pi * 16 + lr) & 63);
      const size_t pbase = (size_t)y * W_ + xx;
#pragma unroll
      for (int r = 0; r < 4; ++r) {
        const int co = cob + ni * 16 + lg * 4 + r;
        const float v = acc[ni][pi][r];
        const float s = 1.f / (1.f + __expf(-v));
        __hip_bfloat16* dst = (co < 64) ? outI : outN;
        dst[((size_t)(b * CC + (co & 63))) * HW + pbase] = __float2bfloat16(s);
      }
    }
  }
}

// ---------------- depthwise conv3x3 (groups=C, pad 1), bf16 in -> fp32 out ----------------
__global__ __launch_bounds__(256) void k_dwconv(
    const __hip_bfloat16* __restrict__ t, const float* __restrict__ wdw, float* __restrict__ out)
{
  const int x_ = threadIdx.x;
  const int y_ = blockIdx.x;
  const int c  = blockIdx.y;
  const int b  = blockIdx.z;
  const bool xm = x_ > 0, xp = x_ < W_ - 1, ym = y_ > 0, yp = y_ < H_ - 1;
  const int oxm = xm ? -1 : 0, oxp = xp ? 1 : 0, oym = ym ? -W_ : 0, oyp = yp ? W_ : 0;
  const float m00 = (ym && xm) ? 1.f : 0.f, m01 = ym ? 1.f : 0.f, m02 = (ym && xp) ? 1.f : 0.f;
  const float m10 = xm ? 1.f : 0.f,                               m12 = xp ? 1.f : 0.f;
  const float m20 = (yp && xm) ? 1.f : 0.f, m21 = yp ? 1.f : 0.f, m22 = (yp && xp) ? 1.f : 0.f;

  const size_t base = ((size_t)(b * CC + c)) * HW + y_ * W_ + x_;
  const __hip_bfloat16* tc = t + base;
  const float* wc = wdw + c * 9;
  float a = 0.f;
  a = fmaf(__bfloat162float(tc[oym + oxm]) * m00, wc[0], a);
  a = fmaf(__bfloat162float(tc[oym      ]) * m01, wc[1], a);
  a = fmaf(__bfloat162float(tc[oym + oxp]) * m02, wc[2], a);
  a = fmaf(__bfloat162float(tc[      oxm]) * m10, wc[3], a);
  a = fmaf(__bfloat162float(tc[0        ])      , wc[4], a);
  a = fmaf(__bfloat162float(tc[      oxp]) * m12, wc[5], a);
  a = fmaf(__bfloat162float(tc[oyp + oxm]) * m20, wc[6], a);
  a = fmaf(__bfloat162float(tc[oyp      ]) * m21, wc[7], a);
  a = fmaf(__bfloat162float(tc[oyp + oxp]) * m22, wc[8], a);
  out[base] = a;
}

// ---------------- channel mean: (B,64,H,W) -> (B,H,W) ----------------
__global__ __launch_bounds__(256) void k_cmean(
    const float* __restrict__ in, float* __restrict__ out)
{
  const int x_ = threadIdx.x;
  const int y_ = blockIdx.x;
  const int b  = blockIdx.y;
  const int p  = y_ * W_ + x_;
  float s = 0.f;
  for (int c = 0; c < CC; ++c) s += in[((size_t)(b * CC + c)) * HW + p];
  out[(size_t)b * HW + p] = s * (1.f / 64.f);
}

// ---------------- conv1x1 (64->64), fp32 ----------------
__global__ __launch_bounds__(256) void k_conv1x1(
    const float* __restrict__ in, const float* __restrict__ w, float* __restrict__ out)
{
  const int x_ = threadIdx.x;
  const int y_ = blockIdx.x;
  const int b  = blockIdx.y;
  const int p  = y_ * W_ + x_;
  const float* ib = in + (size_t)b * CC * HW + p;
  float acc[CC];
#pragma unroll
  for (int i = 0; i < CC; ++i) acc[i] = 0.f;
  for (int ci0 = 0; ci0 < CC; ci0 += 4) {
    const float v0 = ib[(ci0 + 0) * HW], v1 = ib[(ci0 + 1) * HW];
    const float v2 = ib[(ci0 + 2) * HW], v3 = ib[(ci0 + 3) * HW];
#pragma unroll
    for (int co = 0; co < CC; ++co) {
      const float4 wv = *reinterpret_cast<const float4*>(w + co * CC + ci0);
      acc[co] = fmaf(v0, wv.x, fmaf(v1, wv.y, fmaf(v2, wv.z, fmaf(v3, wv.w, acc[co]))));
    }
  }
  float* ob = out + (size_t)b * CC * HW + p;
#pragma unroll
  for (int co = 0; co < CC; ++co) ob[co * HW] = acc[co];
}

// ---------------- windowed attention + fused proj ----------------
__global__ __launch_bounds__(512) void k_attn(
    const float* __restrict__ qb, const float* __restrict__ kb, const float* __restrict__ vb,
    const float* __restrict__ sIll, const float* __restrict__ sNoi,
    const float* __restrict__ temp, const float* __restrict__ wproj, float* __restrict__ out)
{
  __shared__ float K_lds[8][64][8];
  __shared__ float V_lds[8][64][8];
  __shared__ float O_lds[64][64];

  const int tid  = threadIdx.x;
  const int h    = tid >> 6;
  const int lane = tid & 63;
  const int b    = blockIdx.y;
  const int wy   = blockIdx.x >> 5, wx = blockIdx.x & 31;
  const int py   = lane >> 3, px = lane & 7;
  const int p    = (wy * 8 + py) * W_ + wx * 8 + px;

  const size_t cbase = ((size_t)b * CC + h * 8) * HW + p;

  float qv[8];
#pragma unroll
  for (int dd = 0; dd < 8; ++dd) qv[dd] = qb[cbase + dd * HW];
  float qn = 0.f;
#pragma unroll
  for (int dd = 0; dd < 8; ++dd) qn += qv[dd] * qv[dd];
  qn = fmaxf(sqrtf(qn), 1e-12f);
  const float qs = (1.f + sIll[(size_t)b * HW + p]) / qn;
#pragma unroll
  for (int dd = 0; dd < 8; ++dd) qv[dd] *= qs;

  float kv[8];
#pragma unroll
  for (int dd = 0; dd < 8; ++dd) kv[dd] = kb[cbase + dd * HW];
  float kn = 0.f;
#pragma unroll
  for (int dd = 0; dd < 8; ++dd) kn += kv[dd] * kv[dd];
  kn = fmaxf(sqrtf(kn), 1e-12f);
  float ks = 1.f - sNoi[(size_t)b * HW + p];
  ks = fminf(fmaxf(ks, 0.f), 1.f) / kn;
#pragma unroll
  for (int dd = 0; dd < 8; ++dd) K_lds[h][lane][dd] = kv[dd] * ks;
#pragma unroll
  for (int dd = 0; dd < 8; ++dd) V_lds[h][lane][dd] = vb[cbase + dd * HW];

  __syncthreads();

  const float sc = 0.3535533905932738f * temp[h];
  float s[64];
#pragma unroll
  for (int kk = 0; kk < 64; ++kk) {
    float d0 = 0.f;
#pragma unroll
    for (int dd = 0; dd < 8; ++dd) d0 = fmaf(qv[dd], K_lds[h][kk][dd], d0);
    s[kk] = d0 * sc;
  }
  float m = s[0];
#pragma unroll
  for (int kk = 1; kk < 64; ++kk) m = fmaxf(m, s[kk]);
  float sum = 0.f;
#pragma unroll
  for (int kk = 0; kk < 64; ++kk) { s[kk] = __expf(s[kk] - m); sum += s[kk]; }
  const float inv = 1.f / sum;

#pragma unroll
  for (int dd = 0; dd < 8; ++dd) {
    float o = 0.f;
#pragma unroll
    for (int kk = 0; kk < 64; ++kk) o = fmaf(s[kk], V_lds[h][kk][dd], o);
    O_lds[h * 8 + dd][lane] = o * inv;
  }
  __syncthreads();

  float pacc[8];
#pragma unroll
  for (int j = 0; j < 8; ++j) pacc[j] = 0.f;
  for (int ci0 = 0; ci0 < CC; ci0 += 4) {
    const float v0 = O_lds[ci0 + 0][lane], v1 = O_lds[ci0 + 1][lane];
    const float v2 = O_lds[ci0 + 2][lane], v3 = O_lds[ci0 + 3][lane];
#pragma unroll
    for (int j = 0; j < 8; ++j) {
      const float4 wv = *reinterpret_cast<const float4*>(wproj + (h * 8 + j) * CC + ci0);
      pacc[j] = fmaf(v0, wv.x, fmaf(v1, wv.y, fmaf(v2, wv.z, fmaf(v3, wv.w, pacc[j]))));
    }
  }
#pragma unroll
  for (int j = 0; j < 8; ++j)
    out[((size_t)b * CC + h * 8 + j) * HW + p] = pacc[j];
}

extern "C" void kernel_launch(void* const* d_in, const int* in_sizes, int n_in,
                              void* d_out, int out_size, void* d_ws, size_t ws_size,
                              hipStream_t stream) {
  const float* x        = (const float*)d_in[0];
  const float* w_iem    = (const float*)d_in[1];
  const float* w_nem    = (const float*)d_in[2];
  const float* w_iem_dw = (const float*)d_in[3];
  const float* w_nem_dw = (const float*)d_in[4];
  const float* w_q      = (const float*)d_in[5];
  const float* w_k      = (const float*)d_in[6];
  const float* w_v      = (const float*)d_in[7];
  const float* w_proj   = (const float*)d_in[8];
  const float* temp     = (const float*)d_in[9];
  float* outp = (float*)d_out;

  float* wsf = (float*)d_ws;
  const size_t PL = (size_t)4 * CC * HW;          // floats per plane (67.1 MB)

  // region R0: bf16 T1 + T2 (exactly one fp32 plane worth), later reused as fp32 Q
  __hip_bfloat16* T1 = (__hip_bfloat16*)wsf;
  __hip_bfloat16* T2 = T1 + (size_t)4 * CC * HW;
  float* bufQ = wsf;                               // aliases T1/T2 after they're dead
  float* bufI = wsf + PL;                          // illum map; later K
  float* bufN = wsf + 2 * PL;                      // noise map; later V
  float* sI   = wsf + 3 * PL;                      // (B,H,W) scalar map
  float* sN   = sI + (size_t)4 * HW;
  __hip_bfloat16* Bt = (__hip_bfloat16*)sI;        // weight staging; dead before cmean writes sI

  dim3 b256(256), b512(512);

  k_wprep        <<<dim3(288),         b256, 0, stream>>>(w_iem, w_nem, Bt);
  k_conv3x3x2_mfma<<<dim3(4, 128, 4),  b512, 0, stream>>>(x, Bt, T1, T2);

  k_dwconv       <<<dim3(256, 64, 4),  b256, 0, stream>>>(T1, w_iem_dw, bufI);
  k_dwconv       <<<dim3(256, 64, 4),  b256, 0, stream>>>(T2, w_nem_dw, bufN);
  k_cmean        <<<dim3(256, 4),      b256, 0, stream>>>(bufI, sI);
  k_cmean        <<<dim3(256, 4),      b256, 0, stream>>>(bufN, sN);

  k_conv1x1      <<<dim3(256, 4),      b256, 0, stream>>>(bufI, w_q, bufQ);   // q (R0, T1/T2 dead)
  k_conv1x1      <<<dim3(256, 4),      b256, 0, stream>>>(bufN, w_k, bufI);   // k (bufI dead)
  k_conv1x1      <<<dim3(256, 4),      b256, 0, stream>>>(x,    w_v, bufN);   // v (bufN dead)

  k_attn<<<dim3(1024, 4), b512, 0, stream>>>(bufQ, bufI, bufN, sI, sN, temp, w_proj, outp);
}

// Round 3
// 340.832 us; speedup vs baseline: 6.3552x; 2.3931x over previous
//
#include <hip/hip_runtime.h>
#include <hip/hip_bf16.h>
#include <math.h>

#define W_ 256
#define H_ 256
#define HW 65536
#define CC 64

typedef __bf16 bf16x8v __attribute__((ext_vector_type(8)));
typedef float  f32x4   __attribute__((ext_vector_type(4)));

__device__ __forceinline__ float bf2f(__hip_bfloat16 h) { return __bfloat162float(h); }
__device__ __forceinline__ float bflo(unsigned u) { return __uint_as_float(u << 16); }
__device__ __forceinline__ float bfhi(unsigned u) { return __uint_as_float(u & 0xffff0000u); }

// ---------------- weight prep: conv weights fp32 OIHW -> Bt[co128][k=tap*64+ci] bf16 ----------------
__global__ __launch_bounds__(256) void k_wprep(
    const float* __restrict__ wi, const float* __restrict__ wn, __hip_bfloat16* __restrict__ Bt)
{
  int i = blockIdx.x * 256 + threadIdx.x;
  if (i >= 128 * 576) return;
  int co = i / 576, k = i - co * 576;
  int tap = k >> 6, ci = k & 63;
  const float* src = (co < 64) ? wi : wn;
  int c = co & 63;
  Bt[i] = __float2bfloat16(src[(c * 64 + ci) * 9 + tap]);
}

// ---------------- weight prep 2: wq,wk,wv,wproj fp32 [co][ci] -> bf16 [4][64][64] ----------------
__global__ __launch_bounds__(256) void k_wprep2(
    const float* __restrict__ wq, const float* __restrict__ wk,
    const float* __restrict__ wv, const float* __restrict__ wp,
    __hip_bfloat16* __restrict__ W)
{
  int i = blockIdx.x * 256 + threadIdx.x;   // < 16384
  int m = i >> 12, e = i & 4095;
  const float* s = (m == 0) ? wq : (m == 1) ? wk : (m == 2) ? wv : wp;
  W[i] = __float2bfloat16(s[e]);
}

// ---------------- fused dual conv3x3 + sigmoid via MFMA; also dumps x interior as bf16 NHWC ----------------
// grid (4, 128, 4). block 512 = 8 waves (4 co-waves x 2 px-waves).
__global__ __launch_bounds__(512) void k_conv3x3x2_mfma(
    const float* __restrict__ x, const __hip_bfloat16* __restrict__ Bt,
    __hip_bfloat16* __restrict__ outI, __hip_bfloat16* __restrict__ outN,
    __hip_bfloat16* __restrict__ xT)
{
  __shared__ __align__(16) char lds[264 * 144];

  const int tid = threadIdx.x;
  const int b = blockIdx.z, ry = blockIdx.y, cx = blockIdx.x;
  const int y0 = ry * 2, x0 = cx * 64;

  const float* xb = x + (size_t)b * CC * HW;
  for (int e = tid; e < 4 * 64 * 66; e += 512) {
    int t1 = e / 66;
    int c  = e - t1 * 66;
    int r  = t1 >> 6, ci = t1 & 63;
    int y  = y0 - 1 + r, xx = x0 - 1 + c;
    float v = 0.f;
    if ((unsigned)y < 256u && (unsigned)xx < 256u)
      v = xb[(size_t)ci * HW + y * W_ + xx];
    *(__hip_bfloat16*)(lds + (r * 66 + c) * 144 + ci * 2) = __float2bfloat16(v);
  }
  __syncthreads();

  // dump interior 2 rows x 64 px x 64 ci -> xT [b][y][x][ci] bf16 (coalesced 32B/thread)
  {
    int rr = tid >> 8;            // 0..1
    int rem = tid & 255;
    int px = rem >> 2, ch = rem & 3;
    const char* srcp = lds + ((rr + 1) * 66 + (px + 1)) * 144 + ch * 32;
    int4 a  = *(const int4*)(srcp);
    int4 b2 = *(const int4*)(srcp + 16);
    __hip_bfloat16* dst = xT + (((size_t)b * 256 + (y0 + rr)) * 256 + (x0 + px)) * 64 + ch * 16;
    *(int4*)(dst) = a;
    *(int4*)(dst + 8) = b2;
  }

  const int wv = tid >> 6, lane = tid & 63;
  const int wn_ = wv & 3;
  const int wm_ = wv >> 2;
  const int cob = wn_ * 32;
  const int pxb = wm_ * 64;
  const int lg = lane >> 4, lr = lane & 15;

  const char* pB[4];
#pragma unroll
  for (int pi = 0; pi < 4; ++pi) {
    int opx = (pxb + pi * 16 + lr) & 63;
    pB[pi] = lds + (wm_ * 66 + opx) * 144 + lg * 16;
  }
  const __hip_bfloat16* wb0 = Bt + (size_t)(cob + lr) * 576 + lg * 8;
  const __hip_bfloat16* wb1 = wb0 + 16 * 576;

  f32x4 acc[2][4];
#pragma unroll
  for (int i = 0; i < 2; ++i)
#pragma unroll
    for (int j = 0; j < 4; ++j) acc[i][j] = (f32x4){0.f, 0.f, 0.f, 0.f};

#pragma unroll
  for (int tap = 0; tap < 9; ++tap) {
    const int dy = tap / 3, dx = tap - dy * 3;
#pragma unroll
    for (int half = 0; half < 2; ++half) {
      const int loff = (dy * 66 + dx) * 144 + half * 64;
      const int koff = tap * 64 + half * 32;
      bf16x8v a0 = *(const bf16x8v*)(wb0 + koff);
      bf16x8v a1 = *(const bf16x8v*)(wb1 + koff);
      bf16x8v b0 = *(const bf16x8v*)(pB[0] + loff);
      bf16x8v b1 = *(const bf16x8v*)(pB[1] + loff);
      bf16x8v b2 = *(const bf16x8v*)(pB[2] + loff);
      bf16x8v b3 = *(const bf16x8v*)(pB[3] + loff);
      acc[0][0] = __builtin_amdgcn_mfma_f32_16x16x32_bf16(a0, b0, acc[0][0], 0, 0, 0);
      acc[0][1] = __builtin_amdgcn_mfma_f32_16x16x32_bf16(a0, b1, acc[0][1], 0, 0, 0);
      acc[0][2] = __builtin_amdgcn_mfma_f32_16x16x32_bf16(a0, b2, acc[0][2], 0, 0, 0);
      acc[0][3] = __builtin_amdgcn_mfma_f32_16x16x32_bf16(a0, b3, acc[0][3], 0, 0, 0);
      acc[1][0] = __builtin_amdgcn_mfma_f32_16x16x32_bf16(a1, b0, acc[1][0], 0, 0, 0);
      acc[1][1] = __builtin_amdgcn_mfma_f32_16x16x32_bf16(a1, b1, acc[1][1], 0, 0, 0);
      acc[1][2] = __builtin_amdgcn_mfma_f32_16x16x32_bf16(a1, b2, acc[1][2], 0, 0, 0);
      acc[1][3] = __builtin_amdgcn_mfma_f32_16x16x32_bf16(a1, b3, acc[1][3], 0, 0, 0);
    }
  }

  const int y = y0 + wm_;
#pragma unroll
  for (int ni = 0; ni < 2; ++ni) {
#pragma unroll
    for (int pi = 0; pi < 4; ++pi) {
      const int xx = x0 + ((pxb + pi * 16 + lr) & 63);
      const size_t pbase = (size_t)y * W_ + xx;
#pragma unroll
      for (int r = 0; r < 4; ++r) {
        const int co = cob + ni * 16 + lg * 4 + r;
        const float v = acc[ni][pi][r];
        const float s = 1.f / (1.f + __expf(-v));
        __hip_bfloat16* dst = (co < 64) ? outI : outN;
        dst[((size_t)(b * CC + (co & 63))) * HW + pbase] = __float2bfloat16(s);
      }
    }
  }
}

// ---------------- dual depthwise conv3x3: T1,T2 (bf16 NCHW) -> illumT,noiseT (bf16 NHWC) ----------------
// grid 1024 flat (XCD-swizzled so y-neighbors share L2), block 256 = one image row.
__global__ __launch_bounds__(256) void k_dwcm(
    const __hip_bfloat16* __restrict__ T1, const __hip_bfloat16* __restrict__ T2,
    const float* __restrict__ w1, const float* __restrict__ w2,
    __hip_bfloat16* __restrict__ o1, __hip_bfloat16* __restrict__ o2)
{
  __shared__ __align__(16) char sm[256 * 144];
  const int u = blockIdx.x;
  const int xcd = u & 7, idx = u >> 3;
  const int flat = xcd * 128 + idx;
  const int y = flat & 255, b = flat >> 8;
  const int px = threadIdx.x;

  const bool xm = px > 0, xp = px < 255, ym = y > 0, yp = y < 255;
  const int oxm = xm ? -1 : 0, oxp = xp ? 1 : 0, oym = ym ? -W_ : 0, oyp = yp ? W_ : 0;
  const float m00 = (ym && xm) ? 1.f : 0.f, m01 = ym ? 1.f : 0.f, m02 = (ym && xp) ? 1.f : 0.f;
  const float m10 = xm ? 1.f : 0.f,                               m12 = xp ? 1.f : 0.f;
  const float m20 = (yp && xm) ? 1.f : 0.f, m21 = yp ? 1.f : 0.f, m22 = (yp && xp) ? 1.f : 0.f;

#pragma unroll
  for (int pass = 0; pass < 2; ++pass) {
    const __hip_bfloat16* T = pass ? T2 : T1;
    const float* wd = pass ? w2 : w1;
    __hip_bfloat16* og = pass ? o2 : o1;
    if (pass) __syncthreads();

    for (int ci = 0; ci < 64; ++ci) {
      const __hip_bfloat16* base = T + ((size_t)(b * CC + ci)) * HW + y * W_ + px;
      const float* wc = wd + ci * 9;
      float a = 0.f;
      a = fmaf(bf2f(base[oym + oxm]) * m00, wc[0], a);
      a = fmaf(bf2f(base[oym      ]) * m01, wc[1], a);
      a = fmaf(bf2f(base[oym + oxp]) * m02, wc[2], a);
      a = fmaf(bf2f(base[      oxm]) * m10, wc[3], a);
      a = fmaf(bf2f(base[0        ])      , wc[4], a);
      a = fmaf(bf2f(base[      oxp]) * m12, wc[5], a);
      a = fmaf(bf2f(base[oyp + oxm]) * m20, wc[6], a);
      a = fmaf(bf2f(base[oyp      ]) * m21, wc[7], a);
      a = fmaf(bf2f(base[oyp + oxp]) * m22, wc[8], a);
      *(__hip_bfloat16*)(sm + px * 144 + ci * 2) = __float2bfloat16(a);
    }
    __syncthreads();

    __hip_bfloat16* orow = og + (((size_t)b * 256 + y) * 256) * 64;
#pragma unroll
    for (int it = 0; it < 8; ++it) {
      int p = threadIdx.x + it * 256;
      int prow = p >> 3, ch = p & 7;
      int4 d = *(const int4*)(sm + prow * 144 + ch * 16);
      *(int4*)(orow + p * 8) = d;
    }
  }
}

// ---------------- mega attention: qkv proj + l2norm/scale + windowed attn + out proj ----------------
// grid (32,32,4) = one 8x8 window per block; 256 thr = 4 waves.
#define LIN0 0
#define LIN1 9216
#define LIN2 18432
#define LQ   27648
#define LK   44032
#define LV   60416
#define LSI  76800
#define LSN  77056
// total 77312 bytes LDS

__global__ __launch_bounds__(256, 2) void k_megaattn(
    const __hip_bfloat16* __restrict__ illumT, const __hip_bfloat16* __restrict__ noiseT,
    const __hip_bfloat16* __restrict__ xT, const __hip_bfloat16* __restrict__ Wall,
    const float* __restrict__ temp, float* __restrict__ out)
{
  __shared__ __align__(16) char sm[77312];
  const int tid = threadIdx.x;
  const int wv = tid >> 6, lane = tid & 63;
  const int lg = lane >> 4, lr = lane & 15;
  const int b = blockIdx.z, wy = blockIdx.y, wx = blockIdx.x;
  const int y0 = wy * 8, x0 = wx * 8;

  // preload weight A-fragments (block-invariant, L2-resident)
  bf16x8v wf[4][2];
#pragma unroll
  for (int m = 0; m < 4; ++m)
#pragma unroll
    for (int ks = 0; ks < 2; ++ks)
      wf[m][ks] = *(const bf16x8v*)(Wall + m * 4096 + (wv * 16 + lr) * 64 + ks * 32 + lg * 8);
  const float t0 = temp[wv * 2], t1 = temp[wv * 2 + 1];

  // stage illum/noise/x window tiles -> LDS [px][ci] bf16, 144B row stride
  const size_t wbase = (((size_t)b * 256 + y0) * 256 + x0) * 64;
  const __hip_bfloat16* srcs[3] = {illumT + wbase, noiseT + wbase, xT + wbase};
#pragma unroll
  for (int s3 = 0; s3 < 3; ++s3) {
#pragma unroll
    for (int it = 0; it < 2; ++it) {
      int p = tid + it * 256;          // 512 x 16B = 8KB
      int py = p >> 6, off = p & 63;
      int4 d = *(const int4*)(srcs[s3] + (size_t)py * 16384 + off * 8);
      int px = py * 8 + (off >> 3);
      *(int4*)(sm + s3 * 9216 + px * 144 + (off & 7) * 16) = d;
    }
  }
  __syncthreads();

  // per-pixel channel means of illum (tid<64) and noise (64<=tid<128)
  if (tid < 128) {
    int s3 = tid >> 6;
    int px = tid & 63;
    const char* row = sm + s3 * 9216 + px * 144;
    float s = 0.f;
#pragma unroll
    for (int j = 0; j < 8; ++j) {
      int4 d = *(const int4*)(row + j * 16);
      s += bflo(d.x) + bfhi(d.x) + bflo(d.y) + bfhi(d.y)
         + bflo(d.z) + bfhi(d.z) + bflo(d.w) + bfhi(d.w);
    }
    *(float*)(sm + (s3 ? LSN : LSI) + px * 4) = s * (1.f / 64.f);
  }
  __syncthreads();

  // q,k,v GEMMs: D[co][px] = W[co][ci] x IN[ci][px]; wave owns co slice [wv*16, wv*16+16)
  const int OB[3] = {LQ, LK, LV};
#pragma unroll
  for (int m = 0; m < 3; ++m) {
    f32x4 acc[4];
#pragma unroll
    for (int pi = 0; pi < 4; ++pi) acc[pi] = (f32x4){0.f, 0.f, 0.f, 0.f};
#pragma unroll
    for (int pi = 0; pi < 4; ++pi)
#pragma unroll
      for (int ks = 0; ks < 2; ++ks) {
        bf16x8v bfr = *(const bf16x8v*)(sm + m * 9216 + (pi * 16 + lr) * 144 + ks * 64 + lg * 16);
        acc[pi] = __builtin_amdgcn_mfma_f32_16x16x32_bf16(wf[m][ks], bfr, acc[pi], 0, 0, 0);
      }
    // epilogue: per (px, head) l2-normalize (q,k) + scale; store fp32 swizzled
#pragma unroll
    for (int pi = 0; pi < 4; ++pi) {
      const int px = pi * 16 + lr;
      float sc = 1.f;
      if (m < 2) {
        float s2 = acc[pi][0] * acc[pi][0] + acc[pi][1] * acc[pi][1]
                 + acc[pi][2] * acc[pi][2] + acc[pi][3] * acc[pi][3];
        float o8 = __shfl_xor(s2, 16);
        float inv = 1.f / fmaxf(sqrtf(s2 + o8), 1e-12f);
        if (m == 0) {
          float si = *(const float*)(sm + LSI + px * 4);
          float th = (lg & 2) ? t1 : t0;
          sc = (1.f + si) * 0.35355339059327373f * th * inv;
        } else {
          float sn = *(const float*)(sm + LSN + px * 4);
          sc = fminf(fmaxf(1.f - sn, 0.f), 1.f) * inv;
        }
      }
      float4 v4;
      v4.x = acc[pi][0] * sc; v4.y = acc[pi][1] * sc;
      v4.z = acc[pi][2] * sc; v4.w = acc[pi][3] * sc;
      const int chunk = (wv * 4 + lg) ^ (px & 15);
      *(float4*)(sm + OB[m] + px * 256 + chunk * 16) = v4;
    }
  }
  __syncthreads();

  // attention: wave wv handles heads 2wv, 2wv+1; lane = query pixel
#pragma unroll
  for (int t = 0; t < 2; ++t) {
    const int h = wv * 2 + t;
    const int c0 = h * 2, c1 = h * 2 + 1;
    const char* qrow = sm + LQ + lane * 256;
    const float4 qa = *(const float4*)(qrow + ((c0 ^ (lane & 15)) * 16));
    const float4 qb = *(const float4*)(qrow + ((c1 ^ (lane & 15)) * 16));
    float s[64];
#pragma unroll
    for (int kk = 0; kk < 64; ++kk) {
      const char* krow = sm + LK + kk * 256;
      const float4 ka = *(const float4*)(krow + ((c0 ^ (kk & 15)) * 16));
      const float4 kb = *(const float4*)(krow + ((c1 ^ (kk & 15)) * 16));
      float d0 = qa.x * ka.x;
      d0 = fmaf(qa.y, ka.y, d0); d0 = fmaf(qa.z, ka.z, d0); d0 = fmaf(qa.w, ka.w, d0);
      d0 = fmaf(qb.x, kb.x, d0); d0 = fmaf(qb.y, kb.y, d0);
      d0 = fmaf(qb.z, kb.z, d0); d0 = fmaf(qb.w, kb.w, d0);
      s[kk] = d0;
    }
    float mx = s[0];
#pragma unroll
    for (int kk = 1; kk < 64; ++kk) mx = fmaxf(mx, s[kk]);
    float sum = 0.f;
#pragma unroll
    for (int kk = 0; kk < 64; ++kk) { s[kk] = __expf(s[kk] - mx); sum += s[kk]; }
    const float inv = 1.f / sum;
    float o[8];
#pragma unroll
    for (int d = 0; d < 8; ++d) o[d] = 0.f;
#pragma unroll
    for (int kk = 0; kk < 64; ++kk) {
      const char* vrow = sm + LV + kk * 256;
      const float4 va = *(const float4*)(vrow + ((c0 ^ (kk & 15)) * 16));
      const float4 vb = *(const float4*)(vrow + ((c1 ^ (kk & 15)) * 16));
      o[0] = fmaf(s[kk], va.x, o[0]); o[1] = fmaf(s[kk], va.y, o[1]);
      o[2] = fmaf(s[kk], va.z, o[2]); o[3] = fmaf(s[kk], va.w, o[3]);
      o[4] = fmaf(s[kk], vb.x, o[4]); o[5] = fmaf(s[kk], vb.y, o[5]);
      o[6] = fmaf(s[kk], vb.z, o[6]); o[7] = fmaf(s[kk], vb.w, o[7]);
    }
    union { __hip_bfloat16 h8[8]; int4 v; } pk;
#pragma unroll
    for (int d = 0; d < 8; ++d) pk.h8[d] = __float2bfloat16(o[d] * inv);
    *(int4*)(sm + LIN0 + lane * 144 + h * 16) = pk.v;   // AO reuses IN0, [px][ci] bf16
  }
  __syncthreads();

  // output projection: D[co][px] = Wp x AO
  {
    f32x4 acc[4];
#pragma unroll
    for (int pi = 0; pi < 4; ++pi) acc[pi] = (f32x4){0.f, 0.f, 0.f, 0.f};
#pragma unroll
    for (int pi = 0; pi < 4; ++pi)
#pragma unroll
      for (int ks = 0; ks < 2; ++ks) {
        bf16x8v bfr = *(const bf16x8v*)(sm + LIN0 + (pi * 16 + lr) * 144 + ks * 64 + lg * 16);
        acc[pi] = __builtin_amdgcn_mfma_f32_16x16x32_bf16(wf[3][ks], bfr, acc[pi], 0, 0, 0);
      }
#pragma unroll
    for (int pi = 0; pi < 4; ++pi) {
      const int px = pi * 16 + lr;
      const int py = px >> 3, pxx = px & 7;
      const int co = wv * 16 + lg * 4;
      float* obase = out + ((size_t)(b * CC + co)) * HW + (size_t)(y0 + py) * W_ + (x0 + pxx);
      obase[0]      = acc[pi][0];
      obase[HW]     = acc[pi][1];
      obase[2 * HW] = acc[pi][2];
      obase[3 * HW] = acc[pi][3];
    }
  }
}

extern "C" void kernel_launch(void* const* d_in, const int* in_sizes, int n_in,
                              void* d_out, int out_size, void* d_ws, size_t ws_size,
                              hipStream_t stream) {
  const float* x        = (const float*)d_in[0];
  const float* w_iem    = (const float*)d_in[1];
  const float* w_nem    = (const float*)d_in[2];
  const float* w_iem_dw = (const float*)d_in[3];
  const float* w_nem_dw = (const float*)d_in[4];
  const float* w_q      = (const float*)d_in[5];
  const float* w_k      = (const float*)d_in[6];
  const float* w_v      = (const float*)d_in[7];
  const float* w_proj   = (const float*)d_in[8];
  const float* temp     = (const float*)d_in[9];
  float* outp = (float*)d_out;

  float* wsf = (float*)d_ws;
  const size_t PLE = (size_t)4 * CC * HW;          // 16,777,216 elements per plane

  __hip_bfloat16* T1     = (__hip_bfloat16*)wsf;                 // bf16 NCHW
  __hip_bfloat16* T2     = T1 + PLE;
  __hip_bfloat16* illumT = (__hip_bfloat16*)(wsf + PLE);         // bf16 NHWC
  __hip_bfloat16* noiseT = illumT + PLE;
  __hip_bfloat16* xT     = (__hip_bfloat16*)(wsf + 2 * PLE);     // bf16 NHWC
  __hip_bfloat16* Bt     = (__hip_bfloat16*)(wsf + 2 * PLE + PLE / 2);
  __hip_bfloat16* Wall   = Bt + 73728;

  dim3 b256(256), b512(512);

  k_wprep         <<<dim3(288),        b256, 0, stream>>>(w_iem, w_nem, Bt);
  k_wprep2        <<<dim3(64),         b256, 0, stream>>>(w_q, w_k, w_v, w_proj, Wall);
  k_conv3x3x2_mfma<<<dim3(4, 128, 4),  b512, 0, stream>>>(x, Bt, T1, T2, xT);
  k_dwcm          <<<dim3(1024),       b256, 0, stream>>>(T1, T2, w_iem_dw, w_nem_dw, illumT, noiseT);
  k_megaattn      <<<dim3(32, 32, 4),  b256, 0, stream>>>(illumT, noiseT, xT, Wall, temp, outp);
}